// Round 4
// baseline (409.813 us; speedup 1.0000x reference)
//
#include <hip/hip_runtime.h>

// SGIntoKGPool: out[b,m,c] = (sum_n adj[b,n,m] * x[b,c,n]) / max(sum_n adj[b,n,m], 1)
// fp32 in / fp32 out. Internal: bf16 MFMA 16x16x32, f32 accumulation; degrees exact fp32.
//
// R4: BARRIER-FREE main loop. Each wave is self-sufficient:
//   wave owns 16m x 64c output slice, stages its own 16m x 64n adj tile into a
//   PRIVATE LDS region (transpose + fp32->bf16), reads its own A-fragments back
//   (wave-internal lgkmcnt only). No __syncthreads => no vmcnt(0) drain => the
//   compiler keeps the depth-2 register prefetch (8 KB/wave) in flight across
//   iterations (fine-grained vmcnt, AITER-style). 4 waves/CU x 8 KB = 32 KB
//   outstanding >> ~9 KB Little's-law need at 10 B/cy/CU HBM share.
// B-fragments: x pre-converted to bf16 in ws (kernel 1), read per-wave from L2.
// Degrees: per-lane fp32 accumulate -> __shfl_xor butterfly (no LDS, no atomics).
// Output written directly (no partials / fin kernel).
//
// LDS swizzle (per-wave 16m x 64n tile, n-pairs packed per dword):
//   dword(m, kd) = 36*m + 4*((kd>>2) ^ ((m>>2)&3)) + (kd&3),  kd = n/2
//   staging ds_write_b64: uniform 4 accesses/bank (b64 minimum, conflict-free)
//   fragment ds_read_b128: uniform 8 lanes/16B-group (b128 minimum, conflict-free)
//   (both enumerated by hand for the 16-row tile)

typedef short bf16x8 __attribute__((ext_vector_type(8)));
typedef float f32x4 __attribute__((ext_vector_type(4)));

#define BZc 8
#define Cc 64
#define Nc 4096
#define Mc 2048
#define BKc 64
#define KIT (Nc / BKc)        // 64 iterations, full N per wave
#define SDW 36                // adjT row stride in dwords
#define WTILE (16 * SDW)      // 576 dwords per wave buffer

// pack two fp32 -> dword, low16 = bf16(a), high16 = bf16(b); +0x8000 round-to-nearest
__device__ __forceinline__ unsigned int pkbf(float a, float b) {
  unsigned int ua = __float_as_uint(a) + 0x8000u;
  unsigned int ub = __float_as_uint(b) + 0x8000u;
  return (ua >> 16) | (ub & 0xffff0000u);
}

// ---- kernel 1: x fp32 -> bf16 into ws ----
__global__ __launch_bounds__(256) void xcvt_kernel(const float* __restrict__ x,
                                                   unsigned int* __restrict__ xb) {
  const int i = (blockIdx.x * 256 + threadIdx.x) * 8;
  float4 a = *(const float4*)(x + i);
  float4 b = *(const float4*)(x + i + 4);
  *(uint4*)(xb + (i >> 1)) = make_uint4(pkbf(a.x, a.y), pkbf(a.z, a.w),
                                        pkbf(b.x, b.y), pkbf(b.z, b.w));
}

// ---- kernel 2: barrier-free main GEMM ----
__global__ __launch_bounds__(256) void sgkg_main(
    const uint4* __restrict__ X,        // ws: x as bf16, (bz, c, n/8) uint4
    const float* __restrict__ adj,      // (BZ, N, M) fp32
    float* __restrict__ out)            // (BZ, M, C) fp32
{
  __shared__ unsigned int adjT[4][2][WTILE];   // per-wave double buffer, 18 KB

  const int t = threadIdx.x;
  const int l = t & 63;
  const int w = t >> 6;

  const int W      = blockIdx.x * 4 + w;   // 1024 waves = 8 bz x 128 m-slices
  const int bz     = W >> 7;
  const int m_base = (W & 127) << 4;

  const int mg  = l & 3;       // m sub-group: m = 4*mg + j
  const int pp  = l >> 2;      // n-quad index: rows 4*pp .. 4*pp+3
  const int l15 = l & 15;
  const int l4  = l >> 4;

  // A global base: n = 4*pp + q, m = m_base + 4*mg
  const float* ap = adj + (size_t)bz * Nc * Mc + (size_t)(4 * pp) * Mc
                        + (m_base + (mg << 2));
  const size_t tstep = (size_t)BKc * Mc;

  unsigned int* wbuf0 = &adjT[w][0][0];
  unsigned int* wbuf1 = &adjT[w][1][0];
  // staging write base: j-th m adds 36*j; b64 covers kd = 2*pp, 2*pp+1
  const int wb = SDW * (mg << 2) + (((pp >> 1) ^ mg) << 2) + ((pp & 1) << 1);

  // A-fragment read offsets (b128): m = l15, k-block = 4*ks + l4
  const int pi  = l15 >> 2;
  const int ra0 = SDW * l15 + ((l4 ^ pi) << 2);
  const int ra1 = SDW * l15 + (((4 + l4) ^ pi) << 2);

  // B bases per c-tile: row c = 16*ct + l15, + l4-th uint4 (8 n)
  const uint4* xq0 = X + (size_t)(bz * Cc +  0 + l15) * (Nc / 8) + l4;
  const uint4* xq1 = X + (size_t)(bz * Cc + 16 + l15) * (Nc / 8) + l4;
  const uint4* xq2 = X + (size_t)(bz * Cc + 32 + l15) * (Nc / 8) + l4;
  const uint4* xq3 = X + (size_t)(bz * Cc + 48 + l15) * (Nc / 8) + l4;

  f32x4 acc0 = {0.f,0.f,0.f,0.f}, acc1 = {0.f,0.f,0.f,0.f};
  f32x4 acc2 = {0.f,0.f,0.f,0.f}, acc3 = {0.f,0.f,0.f,0.f};
  float d0 = 0.f, d1 = 0.f, d2 = 0.f, d3 = 0.f;

  // depth-2 register prefetch: tiles 0 and 1
  float4 A0[4], A1[4];
#pragma unroll
  for (int q = 0; q < 4; ++q) A0[q] = *(const float4*)(ap + q * Mc);
#pragma unroll
  for (int q = 0; q < 4; ++q) A1[q] = *(const float4*)(ap + tstep + q * Mc);

#define HALF(IT, AR, BUF)                                                      \
  {                                                                            \
    const int bix = (IT) << 3;                                                 \
    uint4 Bv0 = xq0[bix],     Bv1 = xq1[bix],     Bv2 = xq2[bix],     Bv3 = xq3[bix];     \
    uint4 Bv4 = xq0[bix + 4], Bv5 = xq1[bix + 4], Bv6 = xq2[bix + 4], Bv7 = xq3[bix + 4]; \
    *(uint2*)(BUF + wb          ) = make_uint2(pkbf(AR[0].x, AR[1].x), pkbf(AR[2].x, AR[3].x)); \
    *(uint2*)(BUF + wb + SDW    ) = make_uint2(pkbf(AR[0].y, AR[1].y), pkbf(AR[2].y, AR[3].y)); \
    *(uint2*)(BUF + wb + 2 * SDW) = make_uint2(pkbf(AR[0].z, AR[1].z), pkbf(AR[2].z, AR[3].z)); \
    *(uint2*)(BUF + wb + 3 * SDW) = make_uint2(pkbf(AR[0].w, AR[1].w), pkbf(AR[2].w, AR[3].w)); \
    d0 += AR[0].x + AR[1].x + AR[2].x + AR[3].x;                               \
    d1 += AR[0].y + AR[1].y + AR[2].y + AR[3].y;                               \
    d2 += AR[0].z + AR[1].z + AR[2].z + AR[3].z;                               \
    d3 += AR[0].w + AR[1].w + AR[2].w + AR[3].w;                               \
    {                                                                          \
      const int nt = ((IT) + 2 < KIT) ? (IT) + 2 : KIT - 1;                    \
      const float* pf = ap + (size_t)nt * tstep;                               \
      _Pragma("unroll")                                                        \
      for (int q = 0; q < 4; ++q) AR[q] = *(const float4*)(pf + q * Mc);       \
    }                                                                          \
    union { uint4 u; bf16x8 v; } bb;                                           \
    bf16x8 af0 = *(const bf16x8*)(BUF + ra0);                                  \
    bb.u = Bv0; acc0 = __builtin_amdgcn_mfma_f32_16x16x32_bf16(af0, bb.v, acc0, 0, 0, 0); \
    bb.u = Bv1; acc1 = __builtin_amdgcn_mfma_f32_16x16x32_bf16(af0, bb.v, acc1, 0, 0, 0); \
    bb.u = Bv2; acc2 = __builtin_amdgcn_mfma_f32_16x16x32_bf16(af0, bb.v, acc2, 0, 0, 0); \
    bb.u = Bv3; acc3 = __builtin_amdgcn_mfma_f32_16x16x32_bf16(af0, bb.v, acc3, 0, 0, 0); \
    bf16x8 af1 = *(const bf16x8*)(BUF + ra1);                                  \
    bb.u = Bv4; acc0 = __builtin_amdgcn_mfma_f32_16x16x32_bf16(af1, bb.v, acc0, 0, 0, 0); \
    bb.u = Bv5; acc1 = __builtin_amdgcn_mfma_f32_16x16x32_bf16(af1, bb.v, acc1, 0, 0, 0); \
    bb.u = Bv6; acc2 = __builtin_amdgcn_mfma_f32_16x16x32_bf16(af1, bb.v, acc2, 0, 0, 0); \
    bb.u = Bv7; acc3 = __builtin_amdgcn_mfma_f32_16x16x32_bf16(af1, bb.v, acc3, 0, 0, 0); \
  }

  for (int it = 0; it < KIT; it += 2) {
    HALF(it,     A0, wbuf0)
    HALF(it + 1, A1, wbuf1)
  }
#undef HALF

  // ---- degree butterfly reduction over the 16 pp-lanes of each mg class ----
  d0 += __shfl_xor(d0, 4);  d0 += __shfl_xor(d0, 8);  d0 += __shfl_xor(d0, 16); d0 += __shfl_xor(d0, 32);
  d1 += __shfl_xor(d1, 4);  d1 += __shfl_xor(d1, 8);  d1 += __shfl_xor(d1, 16); d1 += __shfl_xor(d1, 32);
  d2 += __shfl_xor(d2, 4);  d2 += __shfl_xor(d2, 8);  d2 += __shfl_xor(d2, 16); d2 += __shfl_xor(d2, 32);
  d3 += __shfl_xor(d3, 4);  d3 += __shfl_xor(d3, 8);  d3 += __shfl_xor(d3, 16); d3 += __shfl_xor(d3, 32);

  // lane needs deg[m_local = 4*l4 + r] = d{r} from lane l4 (lane l4 has mg == l4)
  float inv0 = 1.0f / fmaxf(__shfl(d0, l4), 1.0f);
  float inv1 = 1.0f / fmaxf(__shfl(d1, l4), 1.0f);
  float inv2 = 1.0f / fmaxf(__shfl(d2, l4), 1.0f);
  float inv3 = 1.0f / fmaxf(__shfl(d3, l4), 1.0f);

  // ---- store: D layout col c = 16*ct + l15, row m = 4*l4 + r ----
  const size_t ob = (size_t)(bz * Mc + m_base + (l4 << 2)) * Cc + l15;
  f32x4 av[4] = {acc0, acc1, acc2, acc3};
  float iv[4] = {inv0, inv1, inv2, inv3};
#pragma unroll
  for (int ct = 0; ct < 4; ++ct) {
#pragma unroll
    for (int r = 0; r < 4; ++r) {
      out[ob + (size_t)r * Cc + (ct << 4)] = av[ct][r] * iv[r];
    }
  }
}

extern "C" void kernel_launch(void* const* d_in, const int* in_sizes, int n_in,
                              void* d_out, int out_size, void* d_ws, size_t ws_size,
                              hipStream_t stream) {
  const float* x   = (const float*)d_in[0];  // (8,64,64,64) fp32
  const float* adj = (const float*)d_in[1];  // (8,4096,2048) fp32
  float* out       = (float*)d_out;          // (8,2048,64) fp32
  (void)in_sizes; (void)n_in; (void)out_size; (void)ws_size;

  unsigned int* wsX = (unsigned int*)d_ws;   // 4 MB bf16 copy of x

  // 1) x -> bf16 (2,097,152 elems / 8 per thread / 256 per block = 1024 blocks)
  xcvt_kernel<<<dim3(1024), dim3(256), 0, stream>>>(x, wsX);
  // 2) main: 1024 waves / 4 per block = 256 blocks (1 block/CU, wave-independent)
  sgkg_main<<<dim3(256), dim3(256), 0, stream>>>((const uint4*)wsX, adj, out);
}